// Round 5
// baseline (333.951 us; speedup 1.0000x reference)
//
#include <hip/hip_runtime.h>
#include <hip/hip_bf16.h>

#define N_L 256
#define N_Q 65536
#define D_IN 384
#define D_CTX 192
#define HDIM 64
#define MAXA 6

__device__ __forceinline__ void fma4(float& acc, const float4& w, const float4& v) {
    acc = fmaf(w.x, v.x, acc);
    acc = fmaf(w.y, v.y, acc);
    acc = fmaf(w.z, v.z, acc);
    acc = fmaf(w.w, v.w, acc);
}

__device__ __forceinline__ float lgfact(int n) {
    // log(n!) for n in 0..6  (== gammaln(n+1))
    return (n <= 1) ? 0.0f :
           (n == 2) ? 0.6931471805599453f :
           (n == 3) ? 1.7917594692280550f :
           (n == 4) ? 3.1780538303479458f :
           (n == 5) ? 4.7874917427820460f :
                      6.5792512120101010f;
}

__device__ __forceinline__ float rfl_f(float x) {
    return __int_as_float(__builtin_amdgcn_readfirstlane(__float_as_int(x)));
}

// ---------------- Kernel 1: VAE encode/reparam/decode + llm_emb + per-row loss partials ----
__global__ __launch_bounds__(64) void vae_kernel(
    const float* __restrict__ llms,
    const float* __restrict__ fc1_w, const float* __restrict__ fc1_b,
    const float* __restrict__ fc21_w, const float* __restrict__ fc21_b,
    const float* __restrict__ fc22_w, const float* __restrict__ fc22_b,
    const float* __restrict__ fc3_w, const float* __restrict__ fc3_b,
    const float* __restrict__ fc4_w, const float* __restrict__ fc4_b,
    const float* __restrict__ eps,
    float* __restrict__ emb_out, float* __restrict__ mse_row, float* __restrict__ kld_row)
{
    __shared__ __align__(16) float xs[D_IN];
    __shared__ __align__(16) float hs[HDIM];
    __shared__ __align__(16) float zs[HDIM];
    __shared__ __align__(16) float h2s[HDIM];
    const int r = blockIdx.x;
    const int j = threadIdx.x;

    for (int k = j; k < D_IN; k += 64) xs[k] = llms[r * D_IN + k];
    __syncthreads();

    float acc = fc1_b[j];
    {
        const float4* wr = (const float4*)(fc1_w + (size_t)j * D_IN);
        const float4* xr = (const float4*)xs;
        #pragma unroll 8
        for (int k4 = 0; k4 < D_IN / 4; ++k4) { fma4(acc, wr[k4], xr[k4]); }
    }
    float h = fmaxf(acc, 0.0f);
    hs[j] = h;
    __syncthreads();

    float mu = fc21_b[j], lv = fc22_b[j];
    {
        const float4* w1 = (const float4*)(fc21_w + (size_t)j * HDIM);
        const float4* w2 = (const float4*)(fc22_w + (size_t)j * HDIM);
        const float4* hr = (const float4*)hs;
        #pragma unroll
        for (int k4 = 0; k4 < HDIM / 4; ++k4) {
            float4 hh = hr[k4];
            fma4(mu, w1[k4], hh);
            fma4(lv, w2[k4], hh);
        }
    }
    float stdv = expf(0.5f * lv) * 0.1f;
    float z = fmaf(eps[r * HDIM + j], stdv, mu);

    float elv = expf(lv);
    float kt = (1.0f - (-4.60517018598809136f)) + lv - (mu * mu + elv) / 0.01f;
    float ks = kt;
    #pragma unroll
    for (int o = 32; o; o >>= 1) ks += __shfl_xor(ks, o);

    float zsq = z * z;
    #pragma unroll
    for (int o = 32; o; o >>= 1) zsq += __shfl_xor(zsq, o);
    float nrm = fmaxf(sqrtf(zsq), 1e-12f);
    emb_out[r * HDIM + j] = z / nrm;
    zs[j] = z;
    __syncthreads();

    float a3 = fc3_b[j];
    {
        const float4* w3 = (const float4*)(fc3_w + (size_t)j * HDIM);
        const float4* zr = (const float4*)zs;
        #pragma unroll
        for (int k4 = 0; k4 < HDIM / 4; ++k4) { fma4(a3, w3[k4], zr[k4]); }
    }
    float h2 = fmaxf(a3, 0.0f);
    h2s[j] = h2;
    __syncthreads();

    float ms = 0.0f;
    const float4* h2r = (const float4*)h2s;
    #pragma unroll
    for (int m = 0; m < 6; ++m) {
        int o = j + 64 * m;
        float a4 = fc4_b[o];
        const float4* w4 = (const float4*)(fc4_w + (size_t)o * HDIM);
        #pragma unroll
        for (int k4 = 0; k4 < HDIM / 4; ++k4) { fma4(a4, w4[k4], h2r[k4]); }
        float d = a4 - xs[o];
        ms = fmaf(d, d, ms);
    }
    #pragma unroll
    for (int o = 32; o; o >>= 1) ms += __shfl_xor(ms, o);
    if (j == 0) { mse_row[r] = ms; kld_row[r] = ks; }
}

// ---------------- Kernel 2: finalize vae_loss ----------------
__global__ __launch_bounds__(256) void loss_kernel(
    const float* __restrict__ mse_row, const float* __restrict__ kld_row, float* __restrict__ out_loss)
{
    __shared__ float sm[256], sk[256];
    int t = threadIdx.x;
    sm[t] = mse_row[t]; sk[t] = kld_row[t];
    __syncthreads();
    for (int s = 128; s > 0; s >>= 1) {
        if (t < s) { sm[t] += sm[t + s]; sk[t] += sk[t + s]; }
        __syncthreads();
    }
    if (t == 0) {
        float mse = sm[0] / 98304.0f;           // 256*384
        float kld = -0.5f * (sk[0] / 16384.0f); // 256*64
        out_loss[0] = mse + kld;
    }
}

// ---------------- Kernel 3: FUSED routing — ctx embed + scores + softmax + sampling ------
// LDS: ctx_w transposed wt[k*64+j] (48 KB, lane j -> bank j%32: 2-way = free) +
//      per-wave e strips (8 waves x 8 q x 64 = 16 KB). 64 KB total -> 2 blocks/CU.
__global__ __launch_bounds__(512) void route_kernel(
    const float* __restrict__ contexts, const float* __restrict__ ctx_w, const float* __restrict__ ctx_b,
    const float* __restrict__ emb, const int* __restrict__ agent_num, const float* __restrict__ rand_u,
    float* __restrict__ out_sel, float* __restrict__ out_lp)
{
    __shared__ __align__(16) float wt[D_CTX * HDIM];     // wt[k*64+j] = ctx_w[j*192+k]
    __shared__ __align__(16) float elds[8][8 * HDIM];    // per-wave e vectors

    const int tid = threadIdx.x;
    const int lane = tid & 63;
    const int widx = tid >> 6;
    const int l0 = lane << 2;

    // ---- stage ctx_w transposed (one-time; coalesced global reads) ----
    for (int f = tid; f < HDIM * D_CTX; f += 512) {
        int j = f / D_CTX, k = f - j * D_CTX;
        wt[k * HDIM + j] = ctx_w[f];
    }
    __syncthreads();

    const int g = blockIdx.x * 8 + widx;                 // wave id [0, 8192)
    const int q0 = __builtin_amdgcn_readfirstlane(g << 3);
    const float bj = ctx_b[lane];
    float* ew = elds[widx];

    // ---- phase 1: e_j (lane j) for 8 queries; k-ascending fmac (bit-identical to old ctx) ----
    float e[8];
    #pragma unroll
    for (int q = 0; q < 8; ++q) e[q] = bj;
    #pragma unroll 2
    for (int k4 = 0; k4 < D_CTX / 4; ++k4) {
        float4 xv[8];
        #pragma unroll
        for (int q = 0; q < 8; ++q)
            xv[q] = *(const float4*)(contexts + (size_t)(q0 + q) * D_CTX + k4 * 4); // uniform
        float w0 = wt[(k4 * 4 + 0) * HDIM + lane];
        float w1 = wt[(k4 * 4 + 1) * HDIM + lane];
        float w2 = wt[(k4 * 4 + 2) * HDIM + lane];
        float w3 = wt[(k4 * 4 + 3) * HDIM + lane];
        #pragma unroll
        for (int q = 0; q < 8; ++q) {
            e[q] = fmaf(w0, xv[q].x, e[q]);
            e[q] = fmaf(w1, xv[q].y, e[q]);
            e[q] = fmaf(w2, xv[q].z, e[q]);
            e[q] = fmaf(w3, xv[q].w, e[q]);
        }
    }
    {
        float s[8];
        #pragma unroll
        for (int q = 0; q < 8; ++q) s[q] = e[q] * e[q];
        #pragma unroll
        for (int o = 32; o; o >>= 1)
            #pragma unroll
            for (int q = 0; q < 8; ++q) s[q] += __shfl_xor(s[q], o);
        #pragma unroll
        for (int q = 0; q < 8; ++q) {
            e[q] *= 1.0f / fmaxf(sqrtf(s[q]), 1e-12f);
            ew[q * HDIM + lane] = e[q];                  // same-wave write->read, DS in-order
        }
    }

    // ---- phase 2: logits, lane's 4 llms x 8 queries (identical order to round 4) ----
    float4 P[8];
    #pragma unroll
    for (int q = 0; q < 8; ++q) P[q] = make_float4(0.f, 0.f, 0.f, 0.f);

    const float4* embp = (const float4*)(emb + (size_t)l0 * HDIM);
    #pragma unroll
    for (int c = 0; c < 8; ++c) {                        // k-chunks of 8 floats (2 float4)
        float4 m0[2], m1[2], m2[2], m3[2];
        #pragma unroll
        for (int j = 0; j < 2; ++j) {
            int j4 = c * 2 + j;
            m0[j] = embp[j4]; m1[j] = embp[16 + j4]; m2[j] = embp[32 + j4]; m3[j] = embp[48 + j4];
        }
        #pragma unroll
        for (int q = 0; q < 8; ++q) {
            const float4* ep = (const float4*)(ew + q * HDIM);
            #pragma unroll
            for (int j = 0; j < 2; ++j) {
                float4 ev = ep[c * 2 + j];               // uniform LDS -> broadcast, free
                fma4(P[q].x, m0[j], ev);
                fma4(P[q].y, m1[j], ev);
                fma4(P[q].z, m2[j], ev);
                fma4(P[q].w, m3[j], ev);
            }
        }
    }

    // ---- agent counts + uniforms (scalarized) ----
    int Aq[8];
    #pragma unroll
    for (int q = 0; q < 8; ++q)
        Aq[q] = __builtin_amdgcn_readfirstlane(agent_num[q0 + q]);
    float uu[MAXA][8];
    #pragma unroll
    for (int i = 0; i < MAXA; ++i)
        #pragma unroll
        for (int q = 0; q < 8; ++q)
            uu[i][q] = rfl_f(rand_u[i * N_Q + q0 + q]);

    // ---- softmax, 8 queries interleaved (per-query op order unchanged) ----
    {
        float m[8], s[8];
        #pragma unroll
        for (int k = 0; k < 8; ++k) m[k] = fmaxf(fmaxf(P[k].x, P[k].y), fmaxf(P[k].z, P[k].w));
        #pragma unroll
        for (int o = 32; o; o >>= 1)
            #pragma unroll
            for (int k = 0; k < 8; ++k) m[k] = fmaxf(m[k], __shfl_xor(m[k], o));
        #pragma unroll
        for (int k = 0; k < 8; ++k) {
            P[k].x = expf(P[k].x - m[k]); P[k].y = expf(P[k].y - m[k]);
            P[k].z = expf(P[k].z - m[k]); P[k].w = expf(P[k].w - m[k]);
            s[k] = P[k].x + P[k].y + P[k].z + P[k].w;
        }
        #pragma unroll
        for (int o = 32; o; o >>= 1)
            #pragma unroll
            for (int k = 0; k < 8; ++k) s[k] += __shfl_xor(s[k], o);
        #pragma unroll
        for (int k = 0; k < 8; ++k) {
            float inv = 1.0f / s[k];
            P[k].x *= inv; P[k].y *= inv; P[k].z *= inv; P[k].w *= inv;
        }
    }

    // ---- inclusive cumsum, 8 queries interleaved (same per-query scan) ----
    float c0[8], c1[8], c2[8], c3[8];
    {
        float p3[8], t[8];
        #pragma unroll
        for (int k = 0; k < 8; ++k) {
            c0[k] = P[k].x; c1[k] = c0[k] + P[k].y; c2[k] = c1[k] + P[k].z; p3[k] = c2[k] + P[k].w;
            t[k] = p3[k];
        }
        #pragma unroll
        for (int o = 1; o < 64; o <<= 1)
            #pragma unroll
            for (int k = 0; k < 8; ++k) { float v = __shfl_up(t[k], o); if (lane >= o) t[k] += v; }
        #pragma unroll
        for (int k = 0; k < 8; ++k) {
            float base = t[k] - p3[k];
            c0[k] += base; c1[k] += base; c2[k] += base; c3[k] = p3[k] + base;
        }
    }

    // ---- sampling: ballot+popcount; counts nibble-packed (max 6 < 16) ----
    unsigned nib[8] = {0, 0, 0, 0, 0, 0, 0, 0};
    #pragma unroll
    for (int i = 0; i < MAXA; ++i) {
        #pragma unroll
        for (int k = 0; k < 8; ++k) {
            if (i < Aq[k]) {                       // wave-uniform scalar branch
                float u = uu[i][k];
                unsigned long long b0 = __ballot(c0[k] <= u);
                unsigned long long b1 = __ballot(c1[k] <= u);
                unsigned long long b2 = __ballot(c2[k] <= u);
                unsigned long long b3 = __ballot(c3[k] <= u);
                int loc = __popcll(b0) + __popcll(b1) + __popcll(b2) + __popcll(b3);
                int sel = (loc >= N_L) ? 0 : loc;  // numpy argmax(all-False) == 0
                unsigned d = (unsigned)(sel - l0);
                if (d < 4u) nib[k] += 1u << (4 * d);
            }
        }
    }

    // ---- row stores + log-prob terms (same per-query arithmetic/order) ----
    float term[8];
    #pragma unroll
    for (int k = 0; k < 8; ++k) {
        int n0 = nib[k] & 15, n1 = (nib[k] >> 4) & 15, n2 = (nib[k] >> 8) & 15, n3 = (nib[k] >> 12) & 15;
        float4 rowv = make_float4((float)n0, (float)n1, (float)n2, (float)n3);
        *(((float4*)(out_sel + (size_t)(q0 + k) * N_L)) + lane) = rowv;
        float tm = 0.0f;
        if (n0) tm += (float)n0 * logf(P[k].x) - lgfact(n0);
        if (n1) tm += (float)n1 * logf(P[k].y) - lgfact(n1);
        if (n2) tm += (float)n2 * logf(P[k].z) - lgfact(n2);
        if (n3) tm += (float)n3 * logf(P[k].w) - lgfact(n3);
        term[k] = tm;
    }
    #pragma unroll
    for (int o = 32; o; o >>= 1)
        #pragma unroll
        for (int k = 0; k < 8; ++k) term[k] += __shfl_xor(term[k], o);

    if (lane < 8) {
        float rr = term[0];
        int Aa = Aq[0];
        #pragma unroll
        for (int k = 1; k < 8; ++k) {
            if (lane == k) { rr = term[k]; Aa = Aq[k]; }
        }
        out_lp[q0 + lane] = lgfact(Aa) + rr;
    }
}

extern "C" void kernel_launch(void* const* d_in, const int* in_sizes, int n_in,
                              void* d_out, int out_size, void* d_ws, size_t ws_size,
                              hipStream_t stream) {
    const float* llms      = (const float*)d_in[0];
    const float* contexts  = (const float*)d_in[1];
    const int*   agent_i   = (const int*)  d_in[2];
    // d_in[3] agent_num_float unused (int version + table)
    const float* fc1_w  = (const float*)d_in[4];  const float* fc1_b  = (const float*)d_in[5];
    const float* fc21_w = (const float*)d_in[6];  const float* fc21_b = (const float*)d_in[7];
    const float* fc22_w = (const float*)d_in[8];  const float* fc22_b = (const float*)d_in[9];
    const float* fc3_w  = (const float*)d_in[10]; const float* fc3_b  = (const float*)d_in[11];
    const float* fc4_w  = (const float*)d_in[12]; const float* fc4_b  = (const float*)d_in[13];
    const float* ctx_w  = (const float*)d_in[14]; const float* ctx_b  = (const float*)d_in[15];
    const float* noise  = (const float*)d_in[16]; const float* rand_u = (const float*)d_in[17];

    float* out      = (float*)d_out;
    float* out_sel  = out;                          // [65536][256]
    float* out_lp   = out + (size_t)N_Q * N_L;      // [65536]
    float* out_loss = out_lp + N_Q;                 // [1]

    float* emb      = (float*)d_ws;                 // [256][64]
    float* mse_row  = emb + N_L * HDIM;             // [256]
    float* kld_row  = mse_row + N_L;                // [256]

    vae_kernel<<<N_L, 64, 0, stream>>>(llms, fc1_w, fc1_b, fc21_w, fc21_b, fc22_w, fc22_b,
                                       fc3_w, fc3_b, fc4_w, fc4_b, noise,
                                       emb, mse_row, kld_row);
    loss_kernel<<<1, 256, 0, stream>>>(mse_row, kld_row, out_loss);
    route_kernel<<<1024, 512, 0, stream>>>(contexts, ctx_w, ctx_b, emb, agent_i, rand_u,
                                           out_sel, out_lp);
}

// Round 6
// 254.681 us; speedup vs baseline: 1.3113x; 1.3113x over previous
//
#include <hip/hip_runtime.h>
#include <hip/hip_bf16.h>

#define N_L 256
#define N_Q 65536
#define D_IN 384
#define D_CTX 192
#define HDIM 64
#define MAXA 6

__device__ __forceinline__ void fma4(float& acc, const float4& w, const float4& v) {
    acc = fmaf(w.x, v.x, acc);
    acc = fmaf(w.y, v.y, acc);
    acc = fmaf(w.z, v.z, acc);
    acc = fmaf(w.w, v.w, acc);
}

__device__ __forceinline__ float lgfact(int n) {
    // log(n!) for n in 0..6  (== gammaln(n+1))
    return (n <= 1) ? 0.0f :
           (n == 2) ? 0.6931471805599453f :
           (n == 3) ? 1.7917594692280550f :
           (n == 4) ? 3.1780538303479458f :
           (n == 5) ? 4.7874917427820460f :
                      6.5792512120101010f;
}

__device__ __forceinline__ float rfl_f(float x) {
    return __int_as_float(__builtin_amdgcn_readfirstlane(__float_as_int(x)));
}

// ---------------- Kernel 1: VAE + llm embT + ctx_w transpose + per-row loss partials ----
__global__ __launch_bounds__(64) void vae_kernel(
    const float* __restrict__ llms, const float* __restrict__ ctx_w,
    const float* __restrict__ fc1_w, const float* __restrict__ fc1_b,
    const float* __restrict__ fc21_w, const float* __restrict__ fc21_b,
    const float* __restrict__ fc22_w, const float* __restrict__ fc22_b,
    const float* __restrict__ fc3_w, const float* __restrict__ fc3_b,
    const float* __restrict__ fc4_w, const float* __restrict__ fc4_b,
    const float* __restrict__ eps,
    float* __restrict__ ctx_wT, float* __restrict__ embT,
    float* __restrict__ mse_row, float* __restrict__ kld_row)
{
    __shared__ __align__(16) float xs[D_IN];
    __shared__ __align__(16) float hs[HDIM];
    __shared__ __align__(16) float zs[HDIM];
    __shared__ __align__(16) float h2s[HDIM];
    const int r = blockIdx.x;
    const int j = threadIdx.x;

    // side job: transpose ctx_w -> ctx_wT[k*64+j] = ctx_w[j*192+k] (coalesced writes)
    {
        int t = r * 64 + j;
        if (t < D_CTX * HDIM) ctx_wT[t] = ctx_w[(t & 63) * D_CTX + (t >> 6)];
    }

    for (int k = j; k < D_IN; k += 64) xs[k] = llms[r * D_IN + k];
    __syncthreads();

    float acc = fc1_b[j];
    {
        const float4* wr = (const float4*)(fc1_w + (size_t)j * D_IN);
        const float4* xr = (const float4*)xs;
        #pragma unroll 8
        for (int k4 = 0; k4 < D_IN / 4; ++k4) { fma4(acc, wr[k4], xr[k4]); }
    }
    float h = fmaxf(acc, 0.0f);
    hs[j] = h;
    __syncthreads();

    float mu = fc21_b[j], lv = fc22_b[j];
    {
        const float4* w1 = (const float4*)(fc21_w + (size_t)j * HDIM);
        const float4* w2 = (const float4*)(fc22_w + (size_t)j * HDIM);
        const float4* hr = (const float4*)hs;
        #pragma unroll
        for (int k4 = 0; k4 < HDIM / 4; ++k4) {
            float4 hh = hr[k4];
            fma4(mu, w1[k4], hh);
            fma4(lv, w2[k4], hh);
        }
    }
    float stdv = expf(0.5f * lv) * 0.1f;
    float z = fmaf(eps[r * HDIM + j], stdv, mu);

    float elv = expf(lv);
    float kt = (1.0f - (-4.60517018598809136f)) + lv - (mu * mu + elv) / 0.01f;
    float ks = kt;
    #pragma unroll
    for (int o = 32; o; o >>= 1) ks += __shfl_xor(ks, o);

    float zsq = z * z;
    #pragma unroll
    for (int o = 32; o; o >>= 1) zsq += __shfl_xor(zsq, o);
    float nrm = fmaxf(sqrtf(zsq), 1e-12f);
    embT[j * N_L + r] = z / nrm;                 // transposed store (one-time scatter)
    zs[j] = z;
    __syncthreads();

    float a3 = fc3_b[j];
    {
        const float4* w3 = (const float4*)(fc3_w + (size_t)j * HDIM);
        const float4* zr = (const float4*)zs;
        #pragma unroll
        for (int k4 = 0; k4 < HDIM / 4; ++k4) { fma4(a3, w3[k4], zr[k4]); }
    }
    float h2 = fmaxf(a3, 0.0f);
    h2s[j] = h2;
    __syncthreads();

    float ms = 0.0f;
    const float4* h2r = (const float4*)h2s;
    #pragma unroll
    for (int m = 0; m < 6; ++m) {
        int o = j + 64 * m;
        float a4 = fc4_b[o];
        const float4* w4 = (const float4*)(fc4_w + (size_t)o * HDIM);
        #pragma unroll
        for (int k4 = 0; k4 < HDIM / 4; ++k4) { fma4(a4, w4[k4], h2r[k4]); }
        float d = a4 - xs[o];
        ms = fmaf(d, d, ms);
    }
    #pragma unroll
    for (int o = 32; o; o >>= 1) ms += __shfl_xor(ms, o);
    if (j == 0) { mse_row[r] = ms; kld_row[r] = ks; }
}

// ---------------- Kernel 2: FUSED routing — ctx embed + scores + sampling + loss-finalize --
// No big LDS (8 KB e-strips only). All global streams lane-coalesced via ctx_wT / embT.
__global__ __launch_bounds__(256) void route_kernel(
    const float* __restrict__ contexts, const float* __restrict__ ctx_wT, const float* __restrict__ ctx_b,
    const float* __restrict__ embT, const int* __restrict__ agent_num, const float* __restrict__ rand_u,
    const float* __restrict__ mse_row, const float* __restrict__ kld_row,
    float* __restrict__ out_sel, float* __restrict__ out_lp, float* __restrict__ out_loss)
{
    __shared__ __align__(16) float elds[4][8 * HDIM];    // 8 KB

    const int tid = threadIdx.x;
    const int lane = tid & 63;
    const int widx = tid >> 6;
    const int l0 = lane << 2;

    const int g = blockIdx.x * 4 + widx;                 // wave id [0, 8192)
    const int q0 = __builtin_amdgcn_readfirstlane(g << 3);
    float* ew = elds[widx];

    // ---- fold in vae_loss finalize (block 0, wave 0) ----
    if (g == 0) {
        int rr = lane * 4;
        float ms = mse_row[rr] + mse_row[rr + 1] + mse_row[rr + 2] + mse_row[rr + 3];
        float ks = kld_row[rr] + kld_row[rr + 1] + kld_row[rr + 2] + kld_row[rr + 3];
        #pragma unroll
        for (int o = 32; o; o >>= 1) { ms += __shfl_xor(ms, o); ks += __shfl_xor(ks, o); }
        if (lane == 0) out_loss[0] = ms / 98304.0f - 0.5f * (ks / 16384.0f);
    }

    // ---- phase 1: e_j (lane j) for 8 queries; w lane-coalesced from ctx_wT, x uniform ----
    const float bj = ctx_b[lane];
    float e[8];
    #pragma unroll
    for (int q = 0; q < 8; ++q) e[q] = bj;
    #pragma unroll 2
    for (int k4 = 0; k4 < D_CTX / 4; ++k4) {
        float w0 = ctx_wT[(k4 * 4 + 0) * HDIM + lane];
        float w1 = ctx_wT[(k4 * 4 + 1) * HDIM + lane];
        float w2 = ctx_wT[(k4 * 4 + 2) * HDIM + lane];
        float w3 = ctx_wT[(k4 * 4 + 3) * HDIM + lane];
        #pragma unroll
        for (int q = 0; q < 8; ++q) {
            float4 xv = *(const float4*)(contexts + (size_t)(q0 + q) * D_CTX + k4 * 4); // uniform
            e[q] = fmaf(w0, xv.x, e[q]);
            e[q] = fmaf(w1, xv.y, e[q]);
            e[q] = fmaf(w2, xv.z, e[q]);
            e[q] = fmaf(w3, xv.w, e[q]);
        }
    }
    {
        float s[8];
        #pragma unroll
        for (int q = 0; q < 8; ++q) s[q] = e[q] * e[q];
        #pragma unroll
        for (int o = 32; o; o >>= 1)
            #pragma unroll
            for (int q = 0; q < 8; ++q) s[q] += __shfl_xor(s[q], o);
        #pragma unroll
        for (int q = 0; q < 8; ++q) {
            e[q] *= 1.0f / fmaxf(sqrtf(s[q]), 1e-12f);
            ew[q * HDIM + lane] = e[q];                  // same-wave write->read, DS in-order
        }
    }

    // ---- phase 2: logits, lane's 4 llms x 8 queries; embT lane-coalesced, e uniform ----
    float4 P[8];
    #pragma unroll
    for (int q = 0; q < 8; ++q) P[q] = make_float4(0.f, 0.f, 0.f, 0.f);

    #pragma unroll 2
    for (int j4 = 0; j4 < HDIM / 4; ++j4) {
        float4 M0 = *(const float4*)(embT + (size_t)(j4 * 4 + 0) * N_L + l0);  // coalesced
        float4 M1 = *(const float4*)(embT + (size_t)(j4 * 4 + 1) * N_L + l0);
        float4 M2 = *(const float4*)(embT + (size_t)(j4 * 4 + 2) * N_L + l0);
        float4 M3 = *(const float4*)(embT + (size_t)(j4 * 4 + 3) * N_L + l0);
        #pragma unroll
        for (int q = 0; q < 8; ++q) {
            float4 ev = *(const float4*)(ew + q * HDIM + j4 * 4);   // uniform LDS broadcast
            // j-ascending, identical pairing/order to prior rounds
            P[q].x = fmaf(M0.x, ev.x, P[q].x); P[q].x = fmaf(M1.x, ev.y, P[q].x);
            P[q].x = fmaf(M2.x, ev.z, P[q].x); P[q].x = fmaf(M3.x, ev.w, P[q].x);
            P[q].y = fmaf(M0.y, ev.x, P[q].y); P[q].y = fmaf(M1.y, ev.y, P[q].y);
            P[q].y = fmaf(M2.y, ev.z, P[q].y); P[q].y = fmaf(M3.y, ev.w, P[q].y);
            P[q].z = fmaf(M0.z, ev.x, P[q].z); P[q].z = fmaf(M1.z, ev.y, P[q].z);
            P[q].z = fmaf(M2.z, ev.z, P[q].z); P[q].z = fmaf(M3.z, ev.w, P[q].z);
            P[q].w = fmaf(M0.w, ev.x, P[q].w); P[q].w = fmaf(M1.w, ev.y, P[q].w);
            P[q].w = fmaf(M2.w, ev.z, P[q].w); P[q].w = fmaf(M3.w, ev.w, P[q].w);
        }
    }

    // ---- agent counts + uniforms (scalarized) ----
    int Aq[8];
    #pragma unroll
    for (int q = 0; q < 8; ++q)
        Aq[q] = __builtin_amdgcn_readfirstlane(agent_num[q0 + q]);
    float uu[MAXA][8];
    #pragma unroll
    for (int i = 0; i < MAXA; ++i)
        #pragma unroll
        for (int q = 0; q < 8; ++q)
            uu[i][q] = rfl_f(rand_u[i * N_Q + q0 + q]);

    // ---- softmax, 8 queries interleaved (per-query op order unchanged) ----
    {
        float m[8], s[8];
        #pragma unroll
        for (int k = 0; k < 8; ++k) m[k] = fmaxf(fmaxf(P[k].x, P[k].y), fmaxf(P[k].z, P[k].w));
        #pragma unroll
        for (int o = 32; o; o >>= 1)
            #pragma unroll
            for (int k = 0; k < 8; ++k) m[k] = fmaxf(m[k], __shfl_xor(m[k], o));
        #pragma unroll
        for (int k = 0; k < 8; ++k) {
            P[k].x = expf(P[k].x - m[k]); P[k].y = expf(P[k].y - m[k]);
            P[k].z = expf(P[k].z - m[k]); P[k].w = expf(P[k].w - m[k]);
            s[k] = P[k].x + P[k].y + P[k].z + P[k].w;
        }
        #pragma unroll
        for (int o = 32; o; o >>= 1)
            #pragma unroll
            for (int k = 0; k < 8; ++k) s[k] += __shfl_xor(s[k], o);
        #pragma unroll
        for (int k = 0; k < 8; ++k) {
            float inv = 1.0f / s[k];
            P[k].x *= inv; P[k].y *= inv; P[k].z *= inv; P[k].w *= inv;
        }
    }

    // ---- inclusive cumsum, 8 queries interleaved (same per-query scan) ----
    float c0[8], c1[8], c2[8], c3[8];
    {
        float p3[8], t[8];
        #pragma unroll
        for (int k = 0; k < 8; ++k) {
            c0[k] = P[k].x; c1[k] = c0[k] + P[k].y; c2[k] = c1[k] + P[k].z; p3[k] = c2[k] + P[k].w;
            t[k] = p3[k];
        }
        #pragma unroll
        for (int o = 1; o < 64; o <<= 1)
            #pragma unroll
            for (int k = 0; k < 8; ++k) { float v = __shfl_up(t[k], o); if (lane >= o) t[k] += v; }
        #pragma unroll
        for (int k = 0; k < 8; ++k) {
            float base = t[k] - p3[k];
            c0[k] += base; c1[k] += base; c2[k] += base; c3[k] = p3[k] + base;
        }
    }

    // ---- sampling: ballot+popcount; counts nibble-packed (max 6 < 16) ----
    unsigned nib[8] = {0, 0, 0, 0, 0, 0, 0, 0};
    #pragma unroll
    for (int i = 0; i < MAXA; ++i) {
        #pragma unroll
        for (int k = 0; k < 8; ++k) {
            if (i < Aq[k]) {                       // wave-uniform scalar branch
                float u = uu[i][k];
                unsigned long long b0 = __ballot(c0[k] <= u);
                unsigned long long b1 = __ballot(c1[k] <= u);
                unsigned long long b2 = __ballot(c2[k] <= u);
                unsigned long long b3 = __ballot(c3[k] <= u);
                int loc = __popcll(b0) + __popcll(b1) + __popcll(b2) + __popcll(b3);
                int sel = (loc >= N_L) ? 0 : loc;  // numpy argmax(all-False) == 0
                unsigned d = (unsigned)(sel - l0);
                if (d < 4u) nib[k] += 1u << (4 * d);
            }
        }
    }

    // ---- row stores + log-prob terms (same per-query arithmetic/order) ----
    float term[8];
    #pragma unroll
    for (int k = 0; k < 8; ++k) {
        int n0 = nib[k] & 15, n1 = (nib[k] >> 4) & 15, n2 = (nib[k] >> 8) & 15, n3 = (nib[k] >> 12) & 15;
        float4 rowv = make_float4((float)n0, (float)n1, (float)n2, (float)n3);
        *(((float4*)(out_sel + (size_t)(q0 + k) * N_L)) + lane) = rowv;
        float tm = 0.0f;
        if (n0) tm += (float)n0 * logf(P[k].x) - lgfact(n0);
        if (n1) tm += (float)n1 * logf(P[k].y) - lgfact(n1);
        if (n2) tm += (float)n2 * logf(P[k].z) - lgfact(n2);
        if (n3) tm += (float)n3 * logf(P[k].w) - lgfact(n3);
        term[k] = tm;
    }
    #pragma unroll
    for (int o = 32; o; o >>= 1)
        #pragma unroll
        for (int k = 0; k < 8; ++k) term[k] += __shfl_xor(term[k], o);

    if (lane < 8) {
        float rr = term[0];
        int Aa = Aq[0];
        #pragma unroll
        for (int k = 1; k < 8; ++k) {
            if (lane == k) { rr = term[k]; Aa = Aq[k]; }
        }
        out_lp[q0 + lane] = lgfact(Aa) + rr;
    }
}

extern "C" void kernel_launch(void* const* d_in, const int* in_sizes, int n_in,
                              void* d_out, int out_size, void* d_ws, size_t ws_size,
                              hipStream_t stream) {
    const float* llms      = (const float*)d_in[0];
    const float* contexts  = (const float*)d_in[1];
    const int*   agent_i   = (const int*)  d_in[2];
    // d_in[3] agent_num_float unused (int version + table)
    const float* fc1_w  = (const float*)d_in[4];  const float* fc1_b  = (const float*)d_in[5];
    const float* fc21_w = (const float*)d_in[6];  const float* fc21_b = (const float*)d_in[7];
    const float* fc22_w = (const float*)d_in[8];  const float* fc22_b = (const float*)d_in[9];
    const float* fc3_w  = (const float*)d_in[10]; const float* fc3_b  = (const float*)d_in[11];
    const float* fc4_w  = (const float*)d_in[12]; const float* fc4_b  = (const float*)d_in[13];
    const float* ctx_w  = (const float*)d_in[14]; const float* ctx_b  = (const float*)d_in[15];
    const float* noise  = (const float*)d_in[16]; const float* rand_u = (const float*)d_in[17];

    float* out      = (float*)d_out;
    float* out_sel  = out;                          // [65536][256]
    float* out_lp   = out + (size_t)N_Q * N_L;      // [65536]
    float* out_loss = out_lp + N_Q;                 // [1]

    float* ctx_wT   = (float*)d_ws;                 // [192][64]
    float* embT     = ctx_wT + D_CTX * HDIM;        // [64][256]
    float* mse_row  = embT + HDIM * N_L;            // [256]
    float* kld_row  = mse_row + N_L;                // [256]

    vae_kernel<<<N_L, 64, 0, stream>>>(llms, ctx_w, fc1_w, fc1_b, fc21_w, fc21_b, fc22_w, fc22_b,
                                       fc3_w, fc3_b, fc4_w, fc4_b, noise,
                                       ctx_wT, embT, mse_row, kld_row);
    route_kernel<<<2048, 256, 0, stream>>>(contexts, ctx_wT, ctx_b, embT, agent_i, rand_u,
                                           mse_row, kld_row, out_sel, out_lp, out_loss);
}

// Round 7
// 228.327 us; speedup vs baseline: 1.4626x; 1.1154x over previous
//
#include <hip/hip_runtime.h>
#include <hip/hip_bf16.h>

#define N_L 256
#define N_Q 65536
#define D_IN 384
#define D_CTX 192
#define HDIM 64
#define MAXA 6

__device__ __forceinline__ void fma4(float& acc, const float4& w, const float4& v) {
    acc = fmaf(w.x, v.x, acc);
    acc = fmaf(w.y, v.y, acc);
    acc = fmaf(w.z, v.z, acc);
    acc = fmaf(w.w, v.w, acc);
}

__device__ __forceinline__ float lgfact(int n) {
    // log(n!) for n in 0..6  (== gammaln(n+1))
    return (n <= 1) ? 0.0f :
           (n == 2) ? 0.6931471805599453f :
           (n == 3) ? 1.7917594692280550f :
           (n == 4) ? 3.1780538303479458f :
           (n == 5) ? 4.7874917427820460f :
                      6.5792512120101010f;
}

// ---------------- Kernel 1: VAE + llm embT + packed ctx_w transpose + loss partials ----
__global__ __launch_bounds__(64) void vae_kernel(
    const float* __restrict__ llms, const float* __restrict__ ctx_w,
    const float* __restrict__ fc1_w, const float* __restrict__ fc1_b,
    const float* __restrict__ fc21_w, const float* __restrict__ fc21_b,
    const float* __restrict__ fc22_w, const float* __restrict__ fc22_b,
    const float* __restrict__ fc3_w, const float* __restrict__ fc3_b,
    const float* __restrict__ fc4_w, const float* __restrict__ fc4_b,
    const float* __restrict__ eps,
    float* __restrict__ ctx_wP, float* __restrict__ embT,
    float* __restrict__ mse_row, float* __restrict__ kld_row)
{
    __shared__ __align__(16) float xs[D_IN];
    __shared__ __align__(16) float hs[HDIM];
    __shared__ __align__(16) float zs[HDIM];
    __shared__ __align__(16) float h2s[HDIM];
    const int r = blockIdx.x;
    const int j = threadIdx.x;

    // side job: pack-transpose ctx_w -> ctx_wP[(k4*64+j)*4+rr] = ctx_w[j*192+k4*4+rr]
    {
        int f = r * 64 + j;                       // [0, 16384); need [0, 12288)
        if (f < D_CTX * HDIM) {
            int p = f >> 2, rr = f & 3;
            int jc = p & 63, k4 = p >> 6;
            ctx_wP[f] = ctx_w[jc * D_CTX + k4 * 4 + rr];
        }
    }

    for (int k = j; k < D_IN; k += 64) xs[k] = llms[r * D_IN + k];
    __syncthreads();

    float acc = fc1_b[j];
    {
        const float4* wr = (const float4*)(fc1_w + (size_t)j * D_IN);
        const float4* xr = (const float4*)xs;
        #pragma unroll 8
        for (int k4 = 0; k4 < D_IN / 4; ++k4) { fma4(acc, wr[k4], xr[k4]); }
    }
    float h = fmaxf(acc, 0.0f);
    hs[j] = h;
    __syncthreads();

    float mu = fc21_b[j], lv = fc22_b[j];
    {
        const float4* w1 = (const float4*)(fc21_w + (size_t)j * HDIM);
        const float4* w2 = (const float4*)(fc22_w + (size_t)j * HDIM);
        const float4* hr = (const float4*)hs;
        #pragma unroll
        for (int k4 = 0; k4 < HDIM / 4; ++k4) {
            float4 hh = hr[k4];
            fma4(mu, w1[k4], hh);
            fma4(lv, w2[k4], hh);
        }
    }
    float stdv = expf(0.5f * lv) * 0.1f;
    float z = fmaf(eps[r * HDIM + j], stdv, mu);

    float elv = expf(lv);
    float kt = (1.0f - (-4.60517018598809136f)) + lv - (mu * mu + elv) / 0.01f;
    float ks = kt;
    #pragma unroll
    for (int o = 32; o; o >>= 1) ks += __shfl_xor(ks, o);

    float zsq = z * z;
    #pragma unroll
    for (int o = 32; o; o >>= 1) zsq += __shfl_xor(zsq, o);
    float nrm = fmaxf(sqrtf(zsq), 1e-12f);
    embT[j * N_L + r] = z / nrm;                 // transposed store (one-time scatter)
    zs[j] = z;
    __syncthreads();

    float a3 = fc3_b[j];
    {
        const float4* w3 = (const float4*)(fc3_w + (size_t)j * HDIM);
        const float4* zr = (const float4*)zs;
        #pragma unroll
        for (int k4 = 0; k4 < HDIM / 4; ++k4) { fma4(a3, w3[k4], zr[k4]); }
    }
    float h2 = fmaxf(a3, 0.0f);
    h2s[j] = h2;
    __syncthreads();

    float ms = 0.0f;
    const float4* h2r = (const float4*)h2s;
    #pragma unroll
    for (int m = 0; m < 6; ++m) {
        int o = j + 64 * m;
        float a4 = fc4_b[o];
        const float4* w4 = (const float4*)(fc4_w + (size_t)o * HDIM);
        #pragma unroll
        for (int k4 = 0; k4 < HDIM / 4; ++k4) { fma4(a4, w4[k4], h2r[k4]); }
        float d = a4 - xs[o];
        ms = fmaf(d, d, ms);
    }
    #pragma unroll
    for (int o = 32; o; o >>= 1) ms += __shfl_xor(ms, o);
    if (j == 0) { mse_row[r] = ms; kld_row[r] = ks; }
}

// ---------------- Kernel 2: FUSED routing — ctx embed + scores + sampling + loss-finalize --
// Per-wave LDS strip (1600 floats): x-tile (floats 0..1535, float4 view), uu (1536..1583).
// e-strip (floats 0..511) overlays x after x is dead. All DS reads broadcast/2-way = free.
__global__ __launch_bounds__(256) void route_kernel(
    const float* __restrict__ contexts, const float* __restrict__ ctx_wP, const float* __restrict__ ctx_b,
    const float* __restrict__ embT, const int* __restrict__ agent_num, const float* __restrict__ rand_u,
    const float* __restrict__ mse_row, const float* __restrict__ kld_row,
    float* __restrict__ out_sel, float* __restrict__ out_lp, float* __restrict__ out_loss)
{
    __shared__ __align__(16) float lds[4][1600];         // 25.6 KB/block

    const int tid = threadIdx.x;
    const int lane = tid & 63;
    const int widx = tid >> 6;
    const int l0 = lane << 2;

    const int g = blockIdx.x * 4 + widx;                 // wave id [0, 8192)
    const int q0 = __builtin_amdgcn_readfirstlane(g << 3);
    float* myl = lds[widx];

    // ---- stage 8 context rows (6 KB contiguous, fully coalesced) + uniforms ----
    {
        float4* xls = (float4*)myl;
        const float4* cbase = (const float4*)contexts + (size_t)q0 * (D_CTX / 4);
        #pragma unroll
        for (int it = 0; it < 6; ++it) {
            int f = lane + it * 64;                      // [0, 384)
            xls[f] = cbase[f];
        }
        if (lane < 48)
            myl[1536 + lane] = rand_u[(lane >> 3) * N_Q + q0 + (lane & 7)];
    }

    // ---- fold in vae_loss finalize (wave 0 only) ----
    if (g == 0) {
        int rr = lane * 4;
        float ms = mse_row[rr] + mse_row[rr + 1] + mse_row[rr + 2] + mse_row[rr + 3];
        float ks = kld_row[rr] + kld_row[rr + 1] + kld_row[rr + 2] + kld_row[rr + 3];
        #pragma unroll
        for (int o = 32; o; o >>= 1) { ms += __shfl_xor(ms, o); ks += __shfl_xor(ks, o); }
        if (lane == 0) out_loss[0] = ms / 98304.0f - 0.5f * (ks / 16384.0f);
    }

    // ---- agent counts (8 scalar loads, wave-uniform) ----
    int Aq[8];
    #pragma unroll
    for (int q = 0; q < 8; ++q)
        Aq[q] = __builtin_amdgcn_readfirstlane(agent_num[q0 + q]);

    // ---- phase 1: e_j (lane j) for 8 queries; w coalesced b128, x uniform LDS broadcast ----
    const float bj = ctx_b[lane];
    float e[8];
    #pragma unroll
    for (int q = 0; q < 8; ++q) e[q] = bj;
    {
        const float4* wp = (const float4*)ctx_wP;
        const float4* xls = (const float4*)myl;
        #pragma unroll 2
        for (int k4 = 0; k4 < D_CTX / 4; ++k4) {
            float4 w = wp[k4 * HDIM + lane];             // lane-coalesced 1 KB load
            #pragma unroll
            for (int q = 0; q < 8; ++q) {
                float4 xv = xls[q * 48 + k4];            // uniform broadcast ds_read_b128
                e[q] = fmaf(w.x, xv.x, e[q]);
                e[q] = fmaf(w.y, xv.y, e[q]);
                e[q] = fmaf(w.z, xv.z, e[q]);
                e[q] = fmaf(w.w, xv.w, e[q]);
            }
        }
    }
    {
        float s[8];
        #pragma unroll
        for (int q = 0; q < 8; ++q) s[q] = e[q] * e[q];
        #pragma unroll
        for (int o = 32; o; o >>= 1)
            #pragma unroll
            for (int q = 0; q < 8; ++q) s[q] += __shfl_xor(s[q], o);
        #pragma unroll
        for (int q = 0; q < 8; ++q) {
            e[q] *= 1.0f / fmaxf(sqrtf(s[q]), 1e-12f);
            myl[q * HDIM + lane] = e[q];                 // e-strip overlays dead x region
        }
    }

    // ---- phase 2: logits, lane's 4 llms x 8 queries; embT lane-coalesced, e uniform ----
    float4 P[8];
    #pragma unroll
    for (int q = 0; q < 8; ++q) P[q] = make_float4(0.f, 0.f, 0.f, 0.f);

    #pragma unroll 2
    for (int j4 = 0; j4 < HDIM / 4; ++j4) {
        float4 M0 = *(const float4*)(embT + (size_t)(j4 * 4 + 0) * N_L + l0);  // coalesced
        float4 M1 = *(const float4*)(embT + (size_t)(j4 * 4 + 1) * N_L + l0);
        float4 M2 = *(const float4*)(embT + (size_t)(j4 * 4 + 2) * N_L + l0);
        float4 M3 = *(const float4*)(embT + (size_t)(j4 * 4 + 3) * N_L + l0);
        #pragma unroll
        for (int q = 0; q < 8; ++q) {
            float4 ev = *(const float4*)(myl + q * HDIM + j4 * 4);   // uniform LDS broadcast
            // j-ascending, identical pairing/order to prior rounds
            P[q].x = fmaf(M0.x, ev.x, P[q].x); P[q].x = fmaf(M1.x, ev.y, P[q].x);
            P[q].x = fmaf(M2.x, ev.z, P[q].x); P[q].x = fmaf(M3.x, ev.w, P[q].x);
            P[q].y = fmaf(M0.y, ev.x, P[q].y); P[q].y = fmaf(M1.y, ev.y, P[q].y);
            P[q].y = fmaf(M2.y, ev.z, P[q].y); P[q].y = fmaf(M3.y, ev.w, P[q].y);
            P[q].z = fmaf(M0.z, ev.x, P[q].z); P[q].z = fmaf(M1.z, ev.y, P[q].z);
            P[q].z = fmaf(M2.z, ev.z, P[q].z); P[q].z = fmaf(M3.z, ev.w, P[q].z);
            P[q].w = fmaf(M0.w, ev.x, P[q].w); P[q].w = fmaf(M1.w, ev.y, P[q].w);
            P[q].w = fmaf(M2.w, ev.z, P[q].w); P[q].w = fmaf(M3.w, ev.w, P[q].w);
        }
    }

    // ---- softmax, 8 queries interleaved (per-query op order unchanged) ----
    {
        float m[8], s[8];
        #pragma unroll
        for (int k = 0; k < 8; ++k) m[k] = fmaxf(fmaxf(P[k].x, P[k].y), fmaxf(P[k].z, P[k].w));
        #pragma unroll
        for (int o = 32; o; o >>= 1)
            #pragma unroll
            for (int k = 0; k < 8; ++k) m[k] = fmaxf(m[k], __shfl_xor(m[k], o));
        #pragma unroll
        for (int k = 0; k < 8; ++k) {
            P[k].x = expf(P[k].x - m[k]); P[k].y = expf(P[k].y - m[k]);
            P[k].z = expf(P[k].z - m[k]); P[k].w = expf(P[k].w - m[k]);
            s[k] = P[k].x + P[k].y + P[k].z + P[k].w;
        }
        #pragma unroll
        for (int o = 32; o; o >>= 1)
            #pragma unroll
            for (int k = 0; k < 8; ++k) s[k] += __shfl_xor(s[k], o);
        #pragma unroll
        for (int k = 0; k < 8; ++k) {
            float inv = 1.0f / s[k];
            P[k].x *= inv; P[k].y *= inv; P[k].z *= inv; P[k].w *= inv;
        }
    }

    // ---- inclusive cumsum, 8 queries interleaved (same per-query scan) ----
    float c0[8], c1[8], c2[8], c3[8];
    {
        float p3[8], t[8];
        #pragma unroll
        for (int k = 0; k < 8; ++k) {
            c0[k] = P[k].x; c1[k] = c0[k] + P[k].y; c2[k] = c1[k] + P[k].z; p3[k] = c2[k] + P[k].w;
            t[k] = p3[k];
        }
        #pragma unroll
        for (int o = 1; o < 64; o <<= 1)
            #pragma unroll
            for (int k = 0; k < 8; ++k) { float v = __shfl_up(t[k], o); if (lane >= o) t[k] += v; }
        #pragma unroll
        for (int k = 0; k < 8; ++k) {
            float base = t[k] - p3[k];
            c0[k] += base; c1[k] += base; c2[k] += base; c3[k] = p3[k] + base;
        }
    }

    // ---- sampling: ballot+popcount; u from uniform LDS reads; counts nibble-packed ----
    unsigned nib[8] = {0, 0, 0, 0, 0, 0, 0, 0};
    #pragma unroll
    for (int i = 0; i < MAXA; ++i) {
        #pragma unroll
        for (int k = 0; k < 8; ++k) {
            if (i < Aq[k]) {                       // wave-uniform scalar branch
                float u = myl[1536 + i * 8 + k];   // uniform broadcast ds_read
                unsigned long long b0 = __ballot(c0[k] <= u);
                unsigned long long b1 = __ballot(c1[k] <= u);
                unsigned long long b2 = __ballot(c2[k] <= u);
                unsigned long long b3 = __ballot(c3[k] <= u);
                int loc = __popcll(b0) + __popcll(b1) + __popcll(b2) + __popcll(b3);
                int sel = (loc >= N_L) ? 0 : loc;  // numpy argmax(all-False) == 0
                unsigned d = (unsigned)(sel - l0);
                if (d < 4u) nib[k] += 1u << (4 * d);
            }
        }
    }

    // ---- row stores + log-prob terms (same per-query arithmetic/order) ----
    float term[8];
    #pragma unroll
    for (int k = 0; k < 8; ++k) {
        int n0 = nib[k] & 15, n1 = (nib[k] >> 4) & 15, n2 = (nib[k] >> 8) & 15, n3 = (nib[k] >> 12) & 15;
        float4 rowv = make_float4((float)n0, (float)n1, (float)n2, (float)n3);
        *(((float4*)(out_sel + (size_t)(q0 + k) * N_L)) + lane) = rowv;
        float tm = 0.0f;
        if (n0) tm += (float)n0 * logf(P[k].x) - lgfact(n0);
        if (n1) tm += (float)n1 * logf(P[k].y) - lgfact(n1);
        if (n2) tm += (float)n2 * logf(P[k].z) - lgfact(n2);
        if (n3) tm += (float)n3 * logf(P[k].w) - lgfact(n3);
        term[k] = tm;
    }
    #pragma unroll
    for (int o = 32; o; o >>= 1)
        #pragma unroll
        for (int k = 0; k < 8; ++k) term[k] += __shfl_xor(term[k], o);

    if (lane < 8) {
        float rr = term[0];
        int Aa = Aq[0];
        #pragma unroll
        for (int k = 1; k < 8; ++k) {
            if (lane == k) { rr = term[k]; Aa = Aq[k]; }
        }
        out_lp[q0 + lane] = lgfact(Aa) + rr;
    }
}

extern "C" void kernel_launch(void* const* d_in, const int* in_sizes, int n_in,
                              void* d_out, int out_size, void* d_ws, size_t ws_size,
                              hipStream_t stream) {
    const float* llms      = (const float*)d_in[0];
    const float* contexts  = (const float*)d_in[1];
    const int*   agent_i   = (const int*)  d_in[2];
    // d_in[3] agent_num_float unused (int version + table)
    const float* fc1_w  = (const float*)d_in[4];  const float* fc1_b  = (const float*)d_in[5];
    const float* fc21_w = (const float*)d_in[6];  const float* fc21_b = (const float*)d_in[7];
    const float* fc22_w = (const float*)d_in[8];  const float* fc22_b = (const float*)d_in[9];
    const float* fc3_w  = (const float*)d_in[10]; const float* fc3_b  = (const float*)d_in[11];
    const float* fc4_w  = (const float*)d_in[12]; const float* fc4_b  = (const float*)d_in[13];
    const float* ctx_w  = (const float*)d_in[14]; const float* ctx_b  = (const float*)d_in[15];
    const float* noise  = (const float*)d_in[16]; const float* rand_u = (const float*)d_in[17];

    float* out      = (float*)d_out;
    float* out_sel  = out;                          // [65536][256]
    float* out_lp   = out + (size_t)N_Q * N_L;      // [65536]
    float* out_loss = out_lp + N_Q;                 // [1]

    float* ctx_wP   = (float*)d_ws;                 // [48][64] float4 (12288 floats)
    float* embT     = ctx_wP + D_CTX * HDIM;        // [64][256]
    float* mse_row  = embT + HDIM * N_L;            // [256]
    float* kld_row  = mse_row + N_L;                // [256]

    vae_kernel<<<N_L, 64, 0, stream>>>(llms, ctx_w, fc1_w, fc1_b, fc21_w, fc21_b, fc22_w, fc22_b,
                                       fc3_w, fc3_b, fc4_w, fc4_b, noise,
                                       ctx_wP, embT, mse_row, kld_row);
    route_kernel<<<2048, 256, 0, stream>>>(contexts, ctx_wP, ctx_b, embT, agent_i, rand_u,
                                           mse_row, kld_row, out_sel, out_lp, out_loss);
}